// Round 3
// baseline (553.795 us; speedup 1.0000x reference)
//
#include <hip/hip_runtime.h>

// Problem constants (from reference): A is (M, C) fp32, C = 256.
#define M_ROWS 262144
#define C_DIM 256

// Pass-1 geometry: 256 blocks x 1024 threads (16 waves = 4/SIMD); each block owns
// 1024 rows of A (split-K), staged in 16 steps of 64 rows. Full 256x256 output per
// block: wave tile 64x64 = 2x2 MFMA 32x32 tiles -> 64 acc VGPRs (fits 4 waves/SIMD).
#define NBLK 256
#define ROWS_PER_BLK 1024
#define KSTEP 64
#define NSTEP (ROWS_PER_BLK / KSTEP)

typedef __attribute__((ext_vector_type(8))) short short8;    // 8 bf16 = 4 VGPRs
typedef __attribute__((ext_vector_type(16))) float f32x16;   // MFMA 32x32 acc

static __device__ __forceinline__ unsigned short f2bf(float x) {
    // round-to-nearest-even fp32 -> bf16 (inputs are finite gaussians; no NaN)
    unsigned int u = __float_as_uint(x);
    u += 0x7FFFu + ((u >> 16) & 1u);
    return (unsigned short)(u >> 16);
}

// ---------------------------------------------------------------------------
// K1: fused  (a) E = A copy (beta==0 fast path, vectorized float4)
//            (b) partial AT*A over this block's 1024 rows via bf16 MFMA
// LDS layout: AT[c][k] bf16 (c=0..255, k=0..63), 16B-slot XOR swizzle:
//   halfword index = c*64 + ((slot ^ (c&7))<<3) + (k&7),  slot = k>>3
// Both MFMA A-frags and B-frags read 16B conflict-free (bank = f(swizzled slot);
// each 8-lane group covers 8 distinct slots = all 32 banks).
// ---------------------------------------------------------------------------
__global__ __launch_bounds__(1024, 4) void k_pass1(const float* __restrict__ A,
                                                   const float* __restrict__ betap,
                                                   float* __restrict__ E,
                                                   float* __restrict__ part,
                                                   int atomic_mode) {
    __shared__ unsigned short AT[2][C_DIM * KSTEP];  // 2 x 32 KiB = 64 KiB

    const int tid = threadIdx.x;
    const int l = tid & 63;
    const int w = tid >> 6;          // wave 0..15
    const int wr = w >> 2;           // row band (64 rows each), 0..3
    const int wc = w & 3;            // col band (64 cols each), 0..3
    const int lane31 = l & 31;
    const int h = l >> 5;            // k-half within MFMA fragment
    const bool copyE = (*betap == 0.0f);
    const size_t mbase = (size_t)blockIdx.x * ROWS_PER_BLK;

    const int c = tid & 255;         // staging: column owned by this thread
    const int mq = tid >> 8;         // staging: row quarter (0..3) of the 64-row step

    f32x16 acc[2][2];
#pragma unroll
    for (int i = 0; i < 2; i++)
#pragma unroll
        for (int j = 0; j < 2; j++)
#pragma unroll
            for (int r = 0; r < 16; r++) acc[i][j][r] = 0.0f;

    auto stage = [&](int s) {
        const size_t m0 = mbase + (size_t)s * KSTEP;
        // (a) vectorized chunk read + E copy (also primes L2 for the re-read)
        const float4* A4 = reinterpret_cast<const float4*>(A) + m0 * (C_DIM / 4);
        float4* E4 = reinterpret_cast<float4*>(E) + m0 * (C_DIM / 4);
        if (copyE) {
#pragma unroll
            for (int j = 0; j < 4; j++) E4[j * 1024 + tid] = A4[j * 1024 + tid];
        } else {
#pragma unroll
            for (int j = 0; j < 4; j++) {
                float4 v = A4[j * 1024 + tid];
                asm volatile("" ::"v"(v.x));  // keep the L2-priming read live
            }
        }
        // (b) transposed bf16 staging: thread reads column c, rows mq*16..+16
        //     (coalesced per row across 256 threads; hits L2 primed above)
        unsigned short* dst = AT[s & 1];
        const float* Ac = A + m0 * C_DIM + c;
#pragma unroll
        for (int j2 = 0; j2 < 2; j2++) {
            const int kb = mq * 16 + j2 * 8;
            unsigned short t0 = f2bf(Ac[(size_t)(kb + 0) * C_DIM]);
            unsigned short t1 = f2bf(Ac[(size_t)(kb + 1) * C_DIM]);
            unsigned short t2 = f2bf(Ac[(size_t)(kb + 2) * C_DIM]);
            unsigned short t3 = f2bf(Ac[(size_t)(kb + 3) * C_DIM]);
            unsigned short t4 = f2bf(Ac[(size_t)(kb + 4) * C_DIM]);
            unsigned short t5 = f2bf(Ac[(size_t)(kb + 5) * C_DIM]);
            unsigned short t6 = f2bf(Ac[(size_t)(kb + 6) * C_DIM]);
            unsigned short t7 = f2bf(Ac[(size_t)(kb + 7) * C_DIM]);
            uint4 v4;
            v4.x = (unsigned)t0 | ((unsigned)t1 << 16);
            v4.y = (unsigned)t2 | ((unsigned)t3 << 16);
            v4.z = (unsigned)t4 | ((unsigned)t5 << 16);
            v4.w = (unsigned)t6 | ((unsigned)t7 << 16);
            const int slot = kb >> 3;
            *reinterpret_cast<uint4*>(&dst[c * KSTEP + ((slot ^ (c & 7)) << 3)]) = v4;
        }
    };

    auto compute = [&](int s) {
        const unsigned short* src = AT[s & 1];
#pragma unroll
        for (int kk = 0; kk < KSTEP; kk += 16) {
            const int slot = (kk >> 3) + h;
            short8 af[2], bf[2];
#pragma unroll
            for (int ti = 0; ti < 2; ti++) {
                const int r = wr * 64 + ti * 32 + lane31;
                af[ti] = *reinterpret_cast<const short8*>(
                    &src[r * KSTEP + ((slot ^ (r & 7)) << 3)]);
            }
#pragma unroll
            for (int tj = 0; tj < 2; tj++) {
                const int cc = wc * 64 + tj * 32 + lane31;
                bf[tj] = *reinterpret_cast<const short8*>(
                    &src[cc * KSTEP + ((slot ^ (cc & 7)) << 3)]);
            }
#pragma unroll
            for (int ti = 0; ti < 2; ti++)
#pragma unroll
                for (int tj = 0; tj < 2; tj++)
                    acc[ti][tj] = __builtin_amdgcn_mfma_f32_32x32x16_bf16(
                        af[ti], bf[tj], acc[ti][tj], 0, 0, 0);
        }
    };

    stage(0);
    __syncthreads();
    for (int s = 0; s < NSTEP; s++) {
        if (s + 1 < NSTEP) stage(s + 1);
        compute(s);
        __syncthreads();
    }

    // epilogue: D layout (32x32 MFMA): col = lane&31, row = (reg&3)+8*(reg>>2)+4*h
#pragma unroll
    for (int ti = 0; ti < 2; ti++)
#pragma unroll
        for (int tj = 0; tj < 2; tj++)
#pragma unroll
            for (int reg = 0; reg < 16; reg++) {
                const int r = wr * 64 + ti * 32 + (reg & 3) + 8 * (reg >> 2) + 4 * h;
                const int cc = wc * 64 + tj * 32 + lane31;
                const float v = acc[ti][tj][reg];
                if (atomic_mode)
                    atomicAdd(&part[r * C_DIM + cc], v);
                else
                    part[(size_t)blockIdx.x * (C_DIM * C_DIM) + r * C_DIM + cc] = v;
            }
}

// ---------------------------------------------------------------------------
// K2: reduce partials + row softmax -> CAG (one block per row)
// ---------------------------------------------------------------------------
__global__ __launch_bounds__(256) void k_softmax(const float* __restrict__ part,
                                                 int P, float* __restrict__ CAG) {
    const int r = blockIdx.x;
    const int cidx = threadIdx.x;
    float s = 0.0f;
    const float* p = part + (size_t)r * C_DIM + cidx;
#pragma unroll 8
    for (int b = 0; b < P; b++) s += p[(size_t)b * (C_DIM * C_DIM)];

    __shared__ float buf[C_DIM];
    buf[cidx] = s;
    __syncthreads();
    for (int off = 128; off; off >>= 1) {
        if (cidx < off) buf[cidx] = fmaxf(buf[cidx], buf[cidx + off]);
        __syncthreads();
    }
    const float mx = buf[0];
    __syncthreads();
    const float e = expf(s - mx);
    buf[cidx] = e;
    __syncthreads();
    for (int off = 128; off; off >>= 1) {
        if (cidx < off) buf[cidx] += buf[cidx + off];
        __syncthreads();
    }
    CAG[(size_t)r * C_DIM + cidx] = e / buf[0];
}

// ---------------------------------------------------------------------------
// K3: general-beta fallback (beta != 0 never happens with the given inputs;
// exits immediately when beta == 0). Correct but slow on purpose.
// ---------------------------------------------------------------------------
__global__ __launch_bounds__(256) void k_general(const float* __restrict__ A,
                                                 const float* __restrict__ betap,
                                                 const float* __restrict__ CAG,
                                                 float* __restrict__ E) {
    const float beta = *betap;
    if (beta == 0.0f) return;
    const size_t total = (size_t)M_ROWS * C_DIM;
    for (size_t o = (size_t)blockIdx.x * blockDim.x + threadIdx.x; o < total;
         o += (size_t)gridDim.x * blockDim.x) {
        const size_t m = o >> 8;
        const int cc = (int)(o & 255);
        const float* Am = A + m * C_DIM;
        const float* Cg = CAG + (size_t)cc * C_DIM;
        float a2 = 0.0f;
        for (int d = 0; d < C_DIM; d++) a2 += Am[d] * Cg[d];
        E[o] = Am[cc] + beta * a2;
    }
}

extern "C" void kernel_launch(void* const* d_in, const int* in_sizes, int n_in,
                              void* d_out, int out_size, void* d_ws, size_t ws_size,
                              hipStream_t stream) {
    const float* A = (const float*)d_in[0];
    const float* betap = (const float*)d_in[1];
    float* E = (float*)d_out;
    float* CAG = (float*)d_out + (size_t)M_ROWS * C_DIM;
    float* wsf = (float*)d_ws;

    const size_t part_bytes = (size_t)NBLK * C_DIM * C_DIM * sizeof(float);  // 64 MiB
    const bool partials = (ws_size >= part_bytes);

    if (!partials) {
        // atomic fallback: zero the 256x256 accumulator
        hipMemsetAsync(d_ws, 0, (size_t)C_DIM * C_DIM * sizeof(float), stream);
    }
    k_pass1<<<NBLK, 1024, 0, stream>>>(A, betap, E, wsf, partials ? 0 : 1);
    k_softmax<<<C_DIM, C_DIM, 0, stream>>>(wsf, partials ? NBLK : 1, CAG);
    k_general<<<2048, 256, 0, stream>>>(A, betap, CAG, E);
}

// Round 7
// 470.127 us; speedup vs baseline: 1.1780x; 1.1780x over previous
//
#include <hip/hip_runtime.h>

// Problem constants (from reference): A is (M, C) fp32, C = 256.
#define M_ROWS 262144
#define C_DIM 256

// Pass-1: 256 blocks x 1024 threads (16 waves = 4/SIMD, 1 block/CU). Each block
// owns 1024 rows (split-K), 16 stages of 64 rows. Full 256x256 output per block;
// wave tile 64x64 = 2x2 MFMA 32x32 -> 64 acc VGPRs.
// Single read of A: float4 row loads feed E-copy AND in-register bf16 transpose
// (ds_write_b16 scatter into swizzled AT). No second global read.
#define NBLK 256
#define ROWS_PER_BLK 1024
#define KSTEP 64
#define NSTEP (ROWS_PER_BLK / KSTEP)

typedef __attribute__((ext_vector_type(8))) short short8;    // 8 bf16 = 4 VGPRs
typedef __attribute__((ext_vector_type(16))) float f32x16;   // MFMA 32x32 acc

static __device__ __forceinline__ unsigned short f2bf(float x) {
    // round-to-nearest-even fp32 -> bf16 (inputs finite gaussians; no NaN)
    unsigned int u = __float_as_uint(x);
    u += 0x7FFFu + ((u >> 16) & 1u);
    return (unsigned short)(u >> 16);
}

// Swizzle key: slot' = slot ^ K(c). Reads (c = base + lane31) get 8 distinct
// slots per 8-lane group -> conflict-free ds_read_b128. Writes (c = 4*lane+i)
// get 8 distinct slots over the wave -> 8-way b16 scatter (acceptable).
static __device__ __forceinline__ int swzK(int c) {
    return (c & 7) ^ ((c >> 3) & 3);
}

__global__ __launch_bounds__(1024, 4) void k_pass1(const float* __restrict__ A,
                                                   const float* __restrict__ betap,
                                                   float* __restrict__ E,
                                                   float* __restrict__ part,
                                                   int atomic_mode) {
    __shared__ unsigned short AT[2][C_DIM * KSTEP];  // 2 x 32 KiB = 64 KiB

    const int tid = threadIdx.x;
    const int l = tid & 63;
    const int w = tid >> 6;          // wave 0..15
    const int wr = w >> 2;           // row band (64 rows), 0..3
    const int wc = w & 3;            // col band (64 cols), 0..3
    const int lane31 = l & 31;
    const int h = l >> 5;            // k-half within MFMA fragment
    const bool copyE = (*betap == 0.0f);
    const size_t mbase = (size_t)blockIdx.x * ROWS_PER_BLK;

    // staging geometry: thread handles float4 f = j*1024+tid of each 64-row
    // stage: row k = j*16 + (tid>>6), columns c0..c0+3 with c0 = (tid&63)*4.
    const int c0 = (tid & 63) * 4;

    f32x16 acc[2][2];
#pragma unroll
    for (int i = 0; i < 2; i++)
#pragma unroll
        for (int j = 0; j < 2; j++)
#pragma unroll
            for (int r = 0; r < 16; r++) acc[i][j][r] = 0.0f;

    const float4* A4 = reinterpret_cast<const float4*>(A) + mbase * (C_DIM / 4);
    float4* E4 = reinterpret_cast<float4*>(E) + mbase * (C_DIM / 4);

    float4 buf[4];
    // prologue: issue stage-0 loads
#pragma unroll
    for (int j = 0; j < 4; j++) buf[j] = A4[j * 1024 + tid];

    for (int s = 0; s < NSTEP; s++) {
        unsigned short* dst = AT[s & 1];
        const int sbase = s * 4096;       // float4 index of stage start
        const int nbase = sbase + 4096;   // next stage
        // commit stage s from regs (cvt + LDS scatter + E-copy), reload s+1
#pragma unroll
        for (int j = 0; j < 4; j++) {
            const float4 old = buf[j];
            const int k = j * 16 + w;
            const int slot = k >> 3;
            const int kw = k & 7;
            // bf16 transpose scatter: 4 u16 writes, 8-way bank conflict max
            dst[(c0 + 0) * KSTEP + ((slot ^ swzK(c0 + 0)) << 3) + kw] = f2bf(old.x);
            dst[(c0 + 1) * KSTEP + ((slot ^ swzK(c0 + 1)) << 3) + kw] = f2bf(old.y);
            dst[(c0 + 2) * KSTEP + ((slot ^ swzK(c0 + 2)) << 3) + kw] = f2bf(old.z);
            dst[(c0 + 3) * KSTEP + ((slot ^ swzK(c0 + 3)) << 3) + kw] = f2bf(old.w);
            if (copyE) E4[sbase + j * 1024 + tid] = old;
            if (s + 1 < NSTEP) buf[j] = A4[nbase + j * 1024 + tid];
        }
        __syncthreads();
        // compute stage s
        const unsigned short* src = AT[s & 1];
#pragma unroll
        for (int kk = 0; kk < KSTEP; kk += 16) {
            const int slot = (kk >> 3) + h;
            short8 af[2], bf[2];
#pragma unroll
            for (int ti = 0; ti < 2; ti++) {
                const int r = wr * 64 + ti * 32 + lane31;
                af[ti] = *reinterpret_cast<const short8*>(
                    &src[r * KSTEP + ((slot ^ swzK(r)) << 3)]);
            }
#pragma unroll
            for (int tj = 0; tj < 2; tj++) {
                const int cc = wc * 64 + tj * 32 + lane31;
                bf[tj] = *reinterpret_cast<const short8*>(
                    &src[cc * KSTEP + ((slot ^ swzK(cc)) << 3)]);
            }
#pragma unroll
            for (int ti = 0; ti < 2; ti++)
#pragma unroll
                for (int tj = 0; tj < 2; tj++)
                    acc[ti][tj] = __builtin_amdgcn_mfma_f32_32x32x16_bf16(
                        af[ti], bf[tj], acc[ti][tj], 0, 0, 0);
        }
        __syncthreads();  // protect AT[s&1] before commit(s+2) reuses parity
    }

    // epilogue: D layout (32x32 MFMA): col = lane&31, row = (reg&3)+8*(reg>>2)+4*h
#pragma unroll
    for (int ti = 0; ti < 2; ti++)
#pragma unroll
        for (int tj = 0; tj < 2; tj++)
#pragma unroll
            for (int reg = 0; reg < 16; reg++) {
                const int r = wr * 64 + ti * 32 + (reg & 3) + 8 * (reg >> 2) + 4 * h;
                const int cc = wc * 64 + tj * 32 + lane31;
                const float v = acc[ti][tj][reg];
                if (atomic_mode)
                    atomicAdd(&part[r * C_DIM + cc], v);
                else
                    part[(size_t)blockIdx.x * (C_DIM * C_DIM) + r * C_DIM + cc] = v;
            }
}

// ---------------------------------------------------------------------------
// K2: reduce partials + row softmax -> CAG (one block per row)
// ---------------------------------------------------------------------------
__global__ __launch_bounds__(256) void k_softmax(const float* __restrict__ part,
                                                 int P, float* __restrict__ CAG) {
    const int r = blockIdx.x;
    const int cidx = threadIdx.x;
    float s = 0.0f;
    const float* p = part + (size_t)r * C_DIM + cidx;
#pragma unroll 8
    for (int b = 0; b < P; b++) s += p[(size_t)b * (C_DIM * C_DIM)];

    __shared__ float buf[C_DIM];
    buf[cidx] = s;
    __syncthreads();
    for (int off = 128; off; off >>= 1) {
        if (cidx < off) buf[cidx] = fmaxf(buf[cidx], buf[cidx + off]);
        __syncthreads();
    }
    const float mx = buf[0];
    __syncthreads();
    const float e = expf(s - mx);
    buf[cidx] = e;
    __syncthreads();
    for (int off = 128; off; off >>= 1) {
        if (cidx < off) buf[cidx] += buf[cidx + off];
        __syncthreads();
    }
    CAG[(size_t)r * C_DIM + cidx] = e / buf[0];
}

// ---------------------------------------------------------------------------
// K3: general-beta fallback (never taken with the given inputs; early exit).
// ---------------------------------------------------------------------------
__global__ __launch_bounds__(256) void k_general(const float* __restrict__ A,
                                                 const float* __restrict__ betap,
                                                 const float* __restrict__ CAG,
                                                 float* __restrict__ E) {
    const float beta = *betap;
    if (beta == 0.0f) return;
    const size_t total = (size_t)M_ROWS * C_DIM;
    for (size_t o = (size_t)blockIdx.x * blockDim.x + threadIdx.x; o < total;
         o += (size_t)gridDim.x * blockDim.x) {
        const size_t m = o >> 8;
        const int cc = (int)(o & 255);
        const float* Am = A + m * C_DIM;
        const float* Cg = CAG + (size_t)cc * C_DIM;
        float a2 = 0.0f;
        for (int d = 0; d < C_DIM; d++) a2 += Am[d] * Cg[d];
        E[o] = Am[cc] + beta * a2;
    }
}

extern "C" void kernel_launch(void* const* d_in, const int* in_sizes, int n_in,
                              void* d_out, int out_size, void* d_ws, size_t ws_size,
                              hipStream_t stream) {
    const float* A = (const float*)d_in[0];
    const float* betap = (const float*)d_in[1];
    float* E = (float*)d_out;
    float* CAG = (float*)d_out + (size_t)M_ROWS * C_DIM;
    float* wsf = (float*)d_ws;

    const size_t part_bytes = (size_t)NBLK * C_DIM * C_DIM * sizeof(float);  // 64 MiB
    const bool partials = (ws_size >= part_bytes);

    if (!partials) {
        hipMemsetAsync(d_ws, 0, (size_t)C_DIM * C_DIM * sizeof(float), stream);
    }
    k_pass1<<<NBLK, 1024, 0, stream>>>(A, betap, E, wsf, partials ? 0 : 1);
    k_softmax<<<C_DIM, C_DIM, 0, stream>>>(wsf, partials ? NBLK : 1, CAG);
    k_general<<<2048, 256, 0, stream>>>(A, betap, CAG, E);
}